// Round 7
// baseline (8227.920 us; speedup 1.0000x reference)
//
#include <hip/hip_runtime.h>
#include <hip/hip_bf16.h>
#include <hip/hip_cooperative_groups.h>
#include <stdint.h>

namespace cg = cooperative_groups;

// Problem constants
#define NB 64        // batch
#define HD 512       // hidden = embed
#define SD 128       // src len
#define VC 32000     // vocab
#define NSTEP 32     // T-1
#define NKS 2        // K-split for gates GEMM inside scan (768 each)

typedef __attribute__((ext_vector_type(8))) short s16x8;
typedef __attribute__((ext_vector_type(4))) float fx4;

// ---- workspace layout (bytes). total ~40.2 MB ----
static constexpr size_t OFF_H    = 0;                        // f32 [64][512]
static constexpr size_t OFF_C    = OFF_H    + 131072ull*4;   // f32 [64][512]
static constexpr size_t OFF_GP   = OFF_C    + 131072ull*4;   // f32 [2][64][2048] (region sized for 6)
static constexpr size_t OFF_OTP  = OFF_GP   + 786432ull*4;   // f32 (unused, kept for layout)
static constexpr size_t OFF_MASK = OFF_OTP  + 196608ull*4;   // f32 [64][128]
static constexpr size_t OFF_BS   = OFF_MASK + 8192ull*4;     // f32 [2048] b_ih+b_hh
static constexpr size_t OFF_WCAT = OFF_BS   + 2048ull*4;     // bf16 [2048][1536]  (dead after scan -> W_out bf16)
static constexpr size_t OFF_WV   = OFF_WCAT + 3145728ull*2;  // bf16 [512][1536]
static constexpr size_t OFF_EHB  = OFF_WV   + 786432ull*2;   // bf16 [64][128][1024]
static constexpr size_t OFF_ENCP = OFF_EHB  + 8388608ull*2;  // bf16 [8192][512]
static constexpr size_t OFF_YB   = OFF_ENCP + 4194304ull*2;  // bf16 [32][64][512]
static constexpr size_t OFF_ACAT = OFF_YB   + 1048576ull*2;  // bf16 [64][1536] = [y|o|h]
static constexpr size_t OFF_U    = OFF_ACAT + 98304ull*2;    // bf16 [64][1536] = [a|h]
static constexpr size_t OFF_OB   = OFF_U    + 98304ull*2;    // bf16 [32][64][512]

__device__ __forceinline__ float bf2f(short s) {
  return __uint_as_float(((unsigned)(unsigned short)s) << 16);
}
__device__ __forceinline__ short f2bf(float f) {  // round-to-nearest-even
  unsigned u = __float_as_uint(f);
  return (short)((u + 0x7fffu + ((u >> 16) & 1u)) >> 16);
}
// LDS XOR swizzle on 16B chunks: worst-case 2-way conflicts (free per m136)
__device__ __forceinline__ int swz(int row, int chunk) {
  return row * 32 + ((chunk ^ ((row >> 1) & 3)) * 8);  // offset in shorts
}

// ---------- one-time casts / gathers / inits (+ mask canonicalization in block 0) ----------
__global__ void k_setup(const int* tgt, const float* ench, const float* dih, const float* dic,
                        const float* embed, const float* W_ih, const float* W_hh,
                        const float* b_ih, const float* b_hh, const float* W_v,
                        const unsigned char* mraw, char* ws) {
  if (blockIdx.x == 0) {  // mask: detect bool(1B) vs int32 layout, write f32 mask
    __shared__ int flag;
    if (threadIdx.x == 0) flag = 0;
    __syncthreads();
    int any = 0;
    for (int i = threadIdx.x; i < 8192; i += 256)
      if ((i & 3) && mraw[i]) any = 1;   // int32 {0,1} never has nonzero at byte_off%4!=0
    if (any) atomicOr(&flag, 1);
    __syncthreads();
    const bool isBool = (flag != 0);
    const int* mi = (const int*)mraw;
    float* maskF = (float*)(ws + OFF_MASK);
    for (int i = threadIdx.x; i < 8192; i += 256)
      maskF[i] = isBool ? (float)(mraw[i] != 0) : (float)(mi[i] != 0);
  }
  const unsigned N0 = 3145728u;        // Wcat
  const unsigned N1 = N0 + 786432u;    // Wv
  const unsigned N2 = N1 + 8388608u;   // EHb
  const unsigned N3 = N2 + 1048576u;   // Yb
  const unsigned N4 = N3 + 2048u;      // bsum
  const unsigned N5 = N4 + 32768u;     // state init
  short* Wcat = (short*)(ws + OFF_WCAT);
  short* Wv   = (short*)(ws + OFF_WV);
  short* EHb  = (short*)(ws + OFF_EHB);
  short* Yb   = (short*)(ws + OFF_YB);
  float* bsum = (float*)(ws + OFF_BS);
  float* h    = (float*)(ws + OFF_H);
  float* c    = (float*)(ws + OFF_C);
  short* acat = (short*)(ws + OFF_ACAT);
  for (unsigned i = blockIdx.x * 256u + threadIdx.x; i < N5; i += gridDim.x * 256u) {
    if (i < N0) {
      unsigned r = i / 1536u, k = i % 1536u;
      float v = (k < 1024u) ? W_ih[(size_t)r * 1024 + k] : W_hh[(size_t)r * 512 + (k - 1024u)];
      Wcat[i] = f2bf(v);
    } else if (i < N1) {
      unsigned j = i - N0; Wv[j] = f2bf(W_v[j]);
    } else if (i < N2) {
      unsigned j = i - N1; EHb[j] = f2bf(ench[j]);
    } else if (i < N3) {
      unsigned j = i - N2;                       // t*32768 + b*512 + e
      unsigned tt = j >> 15, rem = j & 32767u, bb = rem >> 9, e = rem & 511u;
      int row = tgt[tt * 64 + bb];
      Yb[j] = f2bf(embed[(size_t)row * 512 + e]);
    } else if (i < N4) {
      unsigned j = i - N3; bsum[j] = b_ih[j] + b_hh[j];
    } else {
      unsigned j = i - N4;                       // b*512 + jj
      unsigned bb = j >> 9, jj = j & 511u;
      float hv = dih[j], cv = dic[j];
      h[j] = hv; c[j] = cv;
      acat[bb * 1536 + 1024 + jj] = f2bf(hv);    // h part
      acat[bb * 1536 + 512 + jj]  = 0;           // o_prev = 0
      int row0 = tgt[bb];                        // t = 0 token
      acat[bb * 1536 + jj] = f2bf(embed[(size_t)row0 * 512 + jj]);
    }
  }
}

// ---------- cast W_out f32 -> bf16 into the (dead-after-scan) WCAT region ----------
__global__ __launch_bounds__(256) void k_castw(const float* __restrict__ W, short* __restrict__ out) {
  size_t i0 = ((size_t)blockIdx.x * 256 + threadIdx.x) * 8;  // grid 8000 * 256 * 8 = 16,384,000
  const float4* p = (const float4*)(W + i0);
  float4 a = p[0], b = p[1];
  s16x8 v;
  v[0] = f2bf(a.x); v[1] = f2bf(a.y); v[2] = f2bf(a.z); v[3] = f2bf(a.w);
  v[4] = f2bf(b.x); v[5] = f2bf(b.y); v[6] = f2bf(b.z); v[7] = f2bf(b.w);
  *(s16x8*)(out + i0) = v;
}

// ---------- 128x128 bf16-MFMA GEMM: C[M][N] = A(bf16,MxK) * B(NxK)^T ----------
template<bool B_F32, bool C_BF16>
__global__ __launch_bounds__(256) void k_gemm128(const short* __restrict__ A,
                                                 const void* __restrict__ Bp,
                                                 void* __restrict__ Cp, int K, int ldc) {
  __shared__ short As[128 * 32];
  __shared__ short Bs[128 * 32];
  const int tid = threadIdx.x, wid = tid >> 6, lane = tid & 63;
  const int wm = wid >> 1, wn = wid & 1;
  const int m0 = blockIdx.x * 128, n0 = blockIdx.y * 128;
  const int srow = tid >> 1, shalf = tid & 1;   // 128 rows x 2 halves of 16
  fx4 acc[4][4] = {};
  for (int k0 = 0; k0 < K; k0 += 32) {
    {
      const s16x8* ga = (const s16x8*)(A + (size_t)(m0 + srow) * K + k0 + shalf * 16);
      s16x8 va0 = ga[0], va1 = ga[1];
      s16x8 vb0, vb1;
      if (B_F32) {
        const float4* gb = (const float4*)((const float*)Bp + (size_t)(n0 + srow) * K + k0 + shalf * 16);
        float4 b0 = gb[0], b1 = gb[1], b2 = gb[2], b3 = gb[3];
        vb0[0]=f2bf(b0.x); vb0[1]=f2bf(b0.y); vb0[2]=f2bf(b0.z); vb0[3]=f2bf(b0.w);
        vb0[4]=f2bf(b1.x); vb0[5]=f2bf(b1.y); vb0[6]=f2bf(b1.z); vb0[7]=f2bf(b1.w);
        vb1[0]=f2bf(b2.x); vb1[1]=f2bf(b2.y); vb1[2]=f2bf(b2.z); vb1[3]=f2bf(b2.w);
        vb1[4]=f2bf(b3.x); vb1[5]=f2bf(b3.y); vb1[6]=f2bf(b3.z); vb1[7]=f2bf(b3.w);
      } else {
        const s16x8* gb = (const s16x8*)((const short*)Bp + (size_t)(n0 + srow) * K + k0 + shalf * 16);
        vb0 = gb[0]; vb1 = gb[1];
      }
      *(s16x8*)&As[swz(srow, shalf * 2)]     = va0;
      *(s16x8*)&As[swz(srow, shalf * 2 + 1)] = va1;
      *(s16x8*)&Bs[swz(srow, shalf * 2)]     = vb0;
      *(s16x8*)&Bs[swz(srow, shalf * 2 + 1)] = vb1;
    }
    __syncthreads();
    const int q = lane >> 4, r16 = lane & 15;
    s16x8 af[4], bfr[4];
#pragma unroll
    for (int i = 0; i < 4; ++i) {
      int ra = wm * 64 + i * 16 + r16;
      int rb = wn * 64 + i * 16 + r16;
      af[i]  = *(const s16x8*)&As[swz(ra, q)];
      bfr[i] = *(const s16x8*)&Bs[swz(rb, q)];
    }
#pragma unroll
    for (int i = 0; i < 4; ++i)
#pragma unroll
      for (int j = 0; j < 4; ++j)
        acc[i][j] = __builtin_amdgcn_mfma_f32_16x16x32_bf16(af[i], bfr[j], acc[i][j], 0, 0, 0);
    __syncthreads();
  }
  const int q = lane >> 4, r16 = lane & 15;
#pragma unroll
  for (int i = 0; i < 4; ++i)
#pragma unroll
    for (int j = 0; j < 4; ++j)
#pragma unroll
      for (int r = 0; r < 4; ++r) {
        int row = m0 + wm * 64 + i * 16 + q * 4 + r;
        int col = n0 + wn * 64 + j * 16 + r16;
        float v = acc[i][j][r];
        if (C_BF16) ((short*)Cp)[(size_t)row * ldc + col] = f2bf(v);
        else        ((float*)Cp)[(size_t)row * ldc + col] = v;
      }
}

// ================= scan phases as device functions (shared by cooperative
// k_scan and the per-phase fallback kernels — identical numerics) =============

// Phase A: gates partial GEMM GP[ks][64][2048] = acat x Wcat^T (blk: ct=blk>>1, ks=blk&1, K=768 each)
__device__ __forceinline__ void phaseA_dev(char* ws, int blk, int tid, short* As, short* Bs) {
  const int wid = tid >> 6, lane = tid & 63;
  const int q = lane >> 4, r16 = lane & 15;
  const short* acat = (const short*)(ws + OFF_ACAT);
  const short* Wcat = (const short*)(ws + OFF_WCAT);
  float* gp = (float*)(ws + OFF_GP);
  const int ct = blk >> 1, ks = blk & 1;
  const int n0 = ct * 64;
  const int srow = tid >> 2, schunk = tid & 3;
  fx4 acc[4] = {};
  for (int kt = 0; kt < 24; ++kt) {
    int k0 = ks * 768 + kt * 32;
    *(s16x8*)&As[swz(srow, schunk)] = *(const s16x8*)(acat + (size_t)srow * 1536 + k0 + schunk * 8);
    *(s16x8*)&Bs[swz(srow, schunk)] = *(const s16x8*)(Wcat + (size_t)(n0 + srow) * 1536 + k0 + schunk * 8);
    __syncthreads();
    s16x8 bfrag = *(const s16x8*)&Bs[swz(wid * 16 + r16, q)];
#pragma unroll
    for (int f = 0; f < 4; ++f) {
      s16x8 afrag = *(const s16x8*)&As[swz(f * 16 + r16, q)];
      acc[f] = __builtin_amdgcn_mfma_f32_16x16x32_bf16(afrag, bfrag, acc[f], 0, 0, 0);
    }
    __syncthreads();
  }
  float* out = gp + (size_t)ks * 64 * 2048;
#pragma unroll
  for (int f = 0; f < 4; ++f)
#pragma unroll
    for (int r = 0; r < 4; ++r) {
      int m = f * 16 + q * 4 + r;
      out[(size_t)m * 2048 + n0 + wid * 16 + r16] = acc[f][r];
    }
}

// Phase B: LSTM cell + attention for batch b=blk; writes h,c, acat.h, u=[a|h]
__device__ __forceinline__ void phaseB_dev(char* ws, int blk, int tid,
                                           float* hs, float* es, float* ps, float* red) {
  const int b = blk;
  float* h  = (float*)(ws + OFF_H);
  float* c  = (float*)(ws + OFF_C);
  const float* gp = (const float*)(ws + OFF_GP);
  const float* bs = (const float*)(ws + OFF_BS);
  const float* mf = (const float*)(ws + OFF_MASK);
  const short* encp = (const short*)(ws + OFF_ENCP);
  const short* ehb  = (const short*)(ws + OFF_EHB);
  short* acat = (short*)(ws + OFF_ACAT);
  short* u    = (short*)(ws + OFF_U);

  for (int j = tid; j < 512; j += 256) {
    float g0 = bs[j], g1 = bs[j + 512], g2 = bs[j + 1024], g3 = bs[j + 1536];
#pragma unroll
    for (int kspl = 0; kspl < NKS; ++kspl) {
      const float* p = gp + (size_t)kspl * 64 * 2048 + b * 2048;
      g0 += p[j]; g1 += p[j + 512]; g2 += p[j + 1024]; g3 += p[j + 1536];
    }
    float ig = 1.f / (1.f + __expf(-g0));
    float fg = 1.f / (1.f + __expf(-g1));
    float gg = tanhf(g2);
    float og = 1.f / (1.f + __expf(-g3));
    float cc = fg * c[b * 512 + j] + ig * gg;
    float hh = og * tanhf(cc);
    c[b * 512 + j] = cc;
    h[b * 512 + j] = hh;
    hs[j] = hh;
    short hb = f2bf(hh);
    acat[b * 1536 + 1024 + j] = hb;
    u[b * 1536 + 1024 + j] = hb;
  }
  __syncthreads();
  // e_t: 128 positions x 2 threads, 4 accumulators
  {
    int s = tid >> 1, half = tid & 1;
    const short* er = encp + ((size_t)b * 128 + s) * 512 + half * 256;
    const float* hp = hs + half * 256;
    float a0 = 0.f, a1 = 0.f, a2 = 0.f, a3 = 0.f;
    for (int k = 0; k < 256; k += 32) {
      s16x8 v0 = *(const s16x8*)(er + k);
      s16x8 v1 = *(const s16x8*)(er + k + 8);
      s16x8 v2 = *(const s16x8*)(er + k + 16);
      s16x8 v3 = *(const s16x8*)(er + k + 24);
#pragma unroll
      for (int jj = 0; jj < 8; ++jj) {
        a0 += bf2f(v0[jj]) * hp[k + jj];
        a1 += bf2f(v1[jj]) * hp[k + 8 + jj];
        a2 += bf2f(v2[jj]) * hp[k + 16 + jj];
        a3 += bf2f(v3[jj]) * hp[k + 24 + jj];
      }
    }
    ps[tid] = (a0 + a1) + (a2 + a3);
  }
  __syncthreads();
  if (tid < 128) {
    float e = ps[2 * tid] + ps[2 * tid + 1];
    if (mf[b * 128 + tid] > 0.5f) e = -1e30f;
    es[tid] = e;
  }
  __syncthreads();
  if (tid < 64) {
    float m = fmaxf(es[tid], es[tid + 64]);
    for (int off = 32; off; off >>= 1) m = fmaxf(m, __shfl_xor(m, off));
    if (tid == 0) red[0] = m;
  }
  __syncthreads();
  float m = red[0];
  if (tid < 128) es[tid] = __expf(es[tid] - m);
  __syncthreads();
  if (tid < 64) {
    float s = es[tid] + es[tid + 64];
    for (int off = 32; off; off >>= 1) s += __shfl_xor(s, off);
    if (tid == 0) red[1] = s;
  }
  __syncthreads();
  float inv = 1.f / red[1];
  if (tid < 128) es[tid] *= inv;   // alpha
  __syncthreads();
  // a_t[k] = sum_s alpha[s] * enc_hidden[b][s][k], 4 accumulators
  for (int it = 0; it < 4; ++it) {
    int k = it * 256 + tid;
    const short* col = ehb + (size_t)b * 128 * 1024 + k;
    float a0 = 0.f, a1 = 0.f, a2 = 0.f, a3 = 0.f;
    for (int s = 0; s < 128; s += 4) {
      a0 += es[s]     * bf2f(col[(size_t)s * 1024]);
      a1 += es[s + 1] * bf2f(col[(size_t)(s + 1) * 1024]);
      a2 += es[s + 2] * bf2f(col[(size_t)(s + 2) * 1024]);
      a3 += es[s + 3] * bf2f(col[(size_t)(s + 3) * 1024]);
    }
    u[b * 1536 + k] = f2bf((a0 + a1) + (a2 + a3));
  }
  __syncthreads();   // protect smem before caller reuses it
}

// Phase C: blks 0..7: o_t = tanh(u x Wv^T), write OB[t], acat.o; blks 8..23: acat.y = Yb[t+1]
__device__ __forceinline__ void phaseC_dev(char* ws, int blk, int tid, int t, short* As, short* Bs) {
  const int wid = tid >> 6, lane = tid & 63;
  const int q = lane >> 4, r16 = lane & 15;
  short* acat = (short*)(ws + OFF_ACAT);
  if (blk < 8) {
    const short* u  = (const short*)(ws + OFF_U);
    const short* Wv = (const short*)(ws + OFF_WV);
    short* OB = (short*)(ws + OFF_OB);
    const int n0 = blk * 64;
    const int srow = tid >> 2, schunk = tid & 3;
    fx4 acc[4] = {};
    for (int kt = 0; kt < 48; ++kt) {
      int k0 = kt * 32;
      *(s16x8*)&As[swz(srow, schunk)] = *(const s16x8*)(u  + (size_t)srow * 1536 + k0 + schunk * 8);
      *(s16x8*)&Bs[swz(srow, schunk)] = *(const s16x8*)(Wv + (size_t)(n0 + srow) * 1536 + k0 + schunk * 8);
      __syncthreads();
      s16x8 bfrag = *(const s16x8*)&Bs[swz(wid * 16 + r16, q)];
#pragma unroll
      for (int f = 0; f < 4; ++f) {
        s16x8 afrag = *(const s16x8*)&As[swz(f * 16 + r16, q)];
        acc[f] = __builtin_amdgcn_mfma_f32_16x16x32_bf16(afrag, bfrag, acc[f], 0, 0, 0);
      }
      __syncthreads();
    }
#pragma unroll
    for (int f = 0; f < 4; ++f)
#pragma unroll
      for (int r = 0; r < 4; ++r) {
        int m = f * 16 + q * 4 + r, n = n0 + wid * 16 + r16;
        short ob = f2bf(tanhf(acc[f][r]));
        OB[(size_t)t * 32768 + m * 512 + n] = ob;
        acat[m * 1536 + 512 + n] = ob;           // o_prev for next step
      }
  } else if (blk < 24 && t < 31) {               // next token embedding into acat.y
    const short* yb = (const short*)(ws + OFF_YB);
    int idx = ((blk - 8) * 256 + tid) * 8;       // 16 blocks * 2048 shorts
    int m = idx >> 9, j = idx & 511;
    *(s16x8*)(acat + m * 1536 + j) = *(const s16x8*)(yb + (size_t)(t + 1) * 32768 + idx);
  }
}

// ---------- persistent cooperative scan: 32 steps, 3 grid-syncs each ----------
__global__ __launch_bounds__(256, 1) void k_scan(char* ws) {
  cg::grid_group grid = cg::this_grid();
  const int blk = blockIdx.x, tid = threadIdx.x;
  __shared__ char smem[8192];            // phases alternate: A/C tile staging, B softmax scratch
  short* As = (short*)smem;              // [64*32]
  short* Bs = (short*)(smem + 4096);     // [64*32]
  float* hs  = (float*)smem;             // [512]
  float* es  = (float*)(smem + 2048);    // [128]
  float* ps  = (float*)(smem + 2560);    // [256]
  float* red = (float*)(smem + 3584);    // [2]

  for (int t = 0; t < NSTEP; ++t) {
    phaseA_dev(ws, blk, tid, As, Bs);
    grid.sync();
    phaseB_dev(ws, blk, tid, hs, es, ps, red);
    grid.sync();
    phaseC_dev(ws, blk, tid, t, As, Bs);
    grid.sync();
  }
}

// ---------- fallback: same phases as ordinary kernels (if cooperative launch unavailable) ----------
__global__ __launch_bounds__(256) void k_pA(char* ws) {
  __shared__ short As[64 * 32];
  __shared__ short Bs[64 * 32];
  phaseA_dev(ws, blockIdx.x, threadIdx.x, As, Bs);
}
__global__ __launch_bounds__(256) void k_pB(char* ws) {
  __shared__ float hs[512];
  __shared__ float es[128];
  __shared__ float ps[256];
  __shared__ float red[2];
  phaseB_dev(ws, blockIdx.x, threadIdx.x, hs, es, ps, red);
}
__global__ __launch_bounds__(256) void k_pC(char* ws, int t) {
  __shared__ short As[64 * 32];
  __shared__ short Bs[64 * 32];
  phaseC_dev(ws, blockIdx.x, threadIdx.x, t, As, Bs);
}

extern "C" void kernel_launch(void* const* d_in, const int* in_sizes, int n_in,
                              void* d_out, int out_size, void* d_ws, size_t ws_size,
                              hipStream_t stream) {
  const int*   tgt   = (const int*)d_in[0];
  const float* ench  = (const float*)d_in[1];
  const float* dih   = (const float*)d_in[2];
  const float* dic   = (const float*)d_in[3];
  const unsigned char* mask = (const unsigned char*)d_in[4];
  const float* embed = (const float*)d_in[5];
  const float* W_ih  = (const float*)d_in[6];
  const float* W_hh  = (const float*)d_in[7];
  const float* b_ih  = (const float*)d_in[8];
  const float* b_hh  = (const float*)d_in[9];
  const float* W_att = (const float*)d_in[10];
  const float* W_v   = (const float*)d_in[11];
  const float* W_out = (const float*)d_in[12];
  char* ws = (char*)d_ws;

  hipLaunchKernelGGL(k_setup, dim3(8192), dim3(256), 0, stream,
                     tgt, ench, dih, dic, embed, W_ih, W_hh, b_ih, b_hh, W_v, mask, ws);
  // enc_proj: [8192x1024] x [512x1024]^T -> bf16 [8192][512]
  hipLaunchKernelGGL((k_gemm128<true, true>), dim3(64, 4), dim3(256), 0, stream,
                     (const short*)(ws + OFF_EHB), (const void*)W_att, (void*)(ws + OFF_ENCP), 1024, 512);
  // persistent cooperative scan (all 32 steps in ONE dispatch); fallback to
  // per-phase launches if cooperative launch is rejected (e.g. under capture)
  {
    char* wsp = ws;
    void* kargs[] = { (void*)&wsp };
    hipError_t cerr = hipLaunchCooperativeKernel((const void*)k_scan, dim3(64), dim3(256),
                                                 kargs, 0, stream);
    if (cerr != hipSuccess) {
      for (int t = 0; t < NSTEP; ++t) {
        hipLaunchKernelGGL(k_pA, dim3(64), dim3(256), 0, stream, ws);
        hipLaunchKernelGGL(k_pB, dim3(64), dim3(256), 0, stream, ws);
        hipLaunchKernelGGL(k_pC, dim3(24), dim3(256), 0, stream, ws, t);
      }
    }
  }
  // W_out -> bf16 into dead scan scratch, then P = O[2048x512] x W_out_bf16[32000x512]^T -> f32 d_out
  hipLaunchKernelGGL(k_castw, dim3(8000), dim3(256), 0, stream, W_out, (short*)(ws + OFF_WCAT));
  hipLaunchKernelGGL((k_gemm128<false, false>), dim3(16, 250), dim3(256), 0, stream,
                     (const short*)(ws + OFF_OB), (const void*)(ws + OFF_WCAT), d_out, 512, 32000);
}

// Round 12
// 2527.455 us; speedup vs baseline: 3.2554x; 3.2554x over previous
//
#include <hip/hip_runtime.h>
#include <hip/hip_bf16.h>
#include <stdint.h>

// Problem constants
#define NB 64        // batch
#define HD 512       // hidden = embed
#define SD 128       // src len
#define VC 32000     // vocab
#define NSTEP 32     // T-1

typedef __attribute__((ext_vector_type(8))) short s16x8;
typedef __attribute__((ext_vector_type(4))) float fx4;

// ---- workspace layout (bytes). total ~40.2 MB ----
static constexpr size_t OFF_H    = 0;                        // f32 [64][512] (legacy, unused by scan)
static constexpr size_t OFF_C    = OFF_H    + 131072ull*4;   // f32 [64][512] (legacy)
static constexpr size_t OFF_GP   = OFF_C    + 131072ull*4;   // f32 [64][2048] gates (region sized larger)
static constexpr size_t OFF_OTP  = OFF_GP   + 786432ull*4;   // barrier cnt/gen (first 8 bytes)
static constexpr size_t OFF_MASK = OFF_OTP  + 196608ull*4;   // f32 [64][128]
static constexpr size_t OFF_BS   = OFF_MASK + 8192ull*4;     // f32 [2048] b_ih+b_hh
static constexpr size_t OFF_WCAT = OFF_BS   + 2048ull*4;     // bf16 [2048][1536] (dead after scan -> W_out bf16)
static constexpr size_t OFF_WV   = OFF_WCAT + 3145728ull*2;  // bf16 [512][1536]
static constexpr size_t OFF_EHB  = OFF_WV   + 786432ull*2;   // bf16 [64][128][1024]
static constexpr size_t OFF_ENCP = OFF_EHB  + 8388608ull*2;  // bf16 [8192][512]
static constexpr size_t OFF_YB   = OFF_ENCP + 4194304ull*2;  // bf16 [32][64][512]
static constexpr size_t OFF_ACAT = OFF_YB   + 1048576ull*2;  // bf16 [64][1536] = [y|o|h]
static constexpr size_t OFF_U    = OFF_ACAT + 98304ull*2;    // bf16 [64][1536] = [a|h]
static constexpr size_t OFF_OB   = OFF_U    + 98304ull*2;    // bf16 [32][64][512]

__device__ __forceinline__ float bf2f(short s) {
  return __uint_as_float(((unsigned)(unsigned short)s) << 16);
}
__device__ __forceinline__ short f2bf(float f) {  // round-to-nearest-even
  unsigned u = __float_as_uint(f);
  return (short)((u + 0x7fffu + ((u >> 16) & 1u)) >> 16);
}
// LDS XOR swizzle on 16B chunks (proven in earlier rounds' k_part)
__device__ __forceinline__ int swz(int row, int chunk) {
  return row * 32 + ((chunk ^ ((row >> 1) & 3)) * 8);  // offset in shorts
}

#define SCOPE_AGENT __HIP_MEMORY_SCOPE_AGENT
// hand-rolled sense-reversal grid barrier (64 blocks), agent-scope atomics.
// Release on fetch_add publishes this block's prior writes; acquire on gen
// (transitively, via the last arriver's release of gen) makes ALL blocks'
// writes visible. Spin uses relaxed loads (atomics bypass L1) + s_sleep.
__device__ __forceinline__ void gridbar(unsigned* cnt, unsigned* gen) {
  __syncthreads();
  if (threadIdx.x == 0) {
    unsigned g = __hip_atomic_load(gen, __ATOMIC_RELAXED, SCOPE_AGENT);
    unsigned prev = __hip_atomic_fetch_add(cnt, 1u, __ATOMIC_ACQ_REL, SCOPE_AGENT);
    if (prev == 63u) {               // last arriver: reset then bump generation
      __hip_atomic_store(cnt, 0u, __ATOMIC_RELAXED, SCOPE_AGENT);
      __hip_atomic_store(gen, g + 1u, __ATOMIC_RELEASE, SCOPE_AGENT);
    } else {
      while (__hip_atomic_load(gen, __ATOMIC_RELAXED, SCOPE_AGENT) == g)
        __builtin_amdgcn_s_sleep(2);
      (void)__hip_atomic_load(gen, __ATOMIC_ACQUIRE, SCOPE_AGENT);
    }
  }
  __syncthreads();
}

// ---------- one-time casts / gathers / inits (+ mask canonicalization in block 0) ----------
__global__ void k_setup(const int* tgt, const float* ench, const float* dih, const float* dic,
                        const float* embed, const float* W_ih, const float* W_hh,
                        const float* b_ih, const float* b_hh, const float* W_v,
                        const unsigned char* mraw, char* ws) {
  if (blockIdx.x == 0) {
    if (threadIdx.x == 0) {          // zero the grid-barrier words (ws is 0xAA-poisoned)
      *(unsigned*)(ws + OFF_OTP) = 0u;
      *(unsigned*)(ws + OFF_OTP + 4) = 0u;
    }
    // mask: detect bool(1B) vs int32 layout, write f32 mask
    __shared__ int flag;
    if (threadIdx.x == 0) flag = 0;
    __syncthreads();
    int any = 0;
    for (int i = threadIdx.x; i < 8192; i += 256)
      if ((i & 3) && mraw[i]) any = 1;   // int32 {0,1} never has nonzero at byte_off%4!=0
    if (any) atomicOr(&flag, 1);
    __syncthreads();
    const bool isBool = (flag != 0);
    const int* mi = (const int*)mraw;
    float* maskF = (float*)(ws + OFF_MASK);
    for (int i = threadIdx.x; i < 8192; i += 256)
      maskF[i] = isBool ? (float)(mraw[i] != 0) : (float)(mi[i] != 0);
  }
  const unsigned N0 = 3145728u;        // Wcat
  const unsigned N1 = N0 + 786432u;    // Wv
  const unsigned N2 = N1 + 8388608u;   // EHb
  const unsigned N3 = N2 + 1048576u;   // Yb
  const unsigned N4 = N3 + 2048u;      // bsum
  const unsigned N5 = N4 + 32768u;     // state init
  short* Wcat = (short*)(ws + OFF_WCAT);
  short* Wv   = (short*)(ws + OFF_WV);
  short* EHb  = (short*)(ws + OFF_EHB);
  short* Yb   = (short*)(ws + OFF_YB);
  float* bsum = (float*)(ws + OFF_BS);
  short* acat = (short*)(ws + OFF_ACAT);
  for (unsigned i = blockIdx.x * 256u + threadIdx.x; i < N5; i += gridDim.x * 256u) {
    if (i < N0) {
      unsigned r = i / 1536u, k = i % 1536u;
      float v = (k < 1024u) ? W_ih[(size_t)r * 1024 + k] : W_hh[(size_t)r * 512 + (k - 1024u)];
      Wcat[i] = f2bf(v);
    } else if (i < N1) {
      unsigned j = i - N0; Wv[j] = f2bf(W_v[j]);
    } else if (i < N2) {
      unsigned j = i - N1; EHb[j] = f2bf(ench[j]);
    } else if (i < N3) {
      unsigned j = i - N2;                       // t*32768 + b*512 + e
      unsigned tt = j >> 15, rem = j & 32767u, bb = rem >> 9, e = rem & 511u;
      int row = tgt[tt * 64 + bb];
      Yb[j] = f2bf(embed[(size_t)row * 512 + e]);
    } else if (i < N4) {
      unsigned j = i - N3; bsum[j] = b_ih[j] + b_hh[j];
    } else {
      unsigned j = i - N4;                       // b*512 + jj
      unsigned bb = j >> 9, jj = j & 511u;
      acat[bb * 1536 + 1024 + jj] = f2bf(dih[j]); // h0
      acat[bb * 1536 + 512 + jj]  = 0;            // o_prev = 0
      int row0 = tgt[bb];                         // t = 0 token
      acat[bb * 1536 + jj] = f2bf(embed[(size_t)row0 * 512 + jj]);
    }
  }
}

// ---------- cast W_out f32 -> bf16 into the (dead-after-scan) WCAT region ----------
__global__ __launch_bounds__(256) void k_castw(const float* __restrict__ W, short* __restrict__ out) {
  size_t i0 = ((size_t)blockIdx.x * 256 + threadIdx.x) * 8;  // 8000*256*8 = 16,384,000
  const float4* p = (const float4*)(W + i0);
  float4 a = p[0], b = p[1];
  s16x8 v;
  v[0] = f2bf(a.x); v[1] = f2bf(a.y); v[2] = f2bf(a.z); v[3] = f2bf(a.w);
  v[4] = f2bf(b.x); v[5] = f2bf(b.y); v[6] = f2bf(b.z); v[7] = f2bf(b.w);
  *(s16x8*)(out + i0) = v;
}

// ---------- 128x128 bf16-MFMA GEMM: C[M][N] = A(bf16,MxK) * B(NxK)^T ----------
template<bool B_F32, bool C_BF16>
__global__ __launch_bounds__(256) void k_gemm128(const short* __restrict__ A,
                                                 const void* __restrict__ Bp,
                                                 void* __restrict__ Cp, int K, int ldc) {
  __shared__ short As[128 * 32];
  __shared__ short Bs[128 * 32];
  const int tid = threadIdx.x, wid = tid >> 6, lane = tid & 63;
  const int wm = wid >> 1, wn = wid & 1;
  const int m0 = blockIdx.x * 128, n0 = blockIdx.y * 128;
  const int srow = tid >> 1, shalf = tid & 1;
  fx4 acc[4][4] = {};
  for (int k0 = 0; k0 < K; k0 += 32) {
    {
      const s16x8* ga = (const s16x8*)(A + (size_t)(m0 + srow) * K + k0 + shalf * 16);
      s16x8 va0 = ga[0], va1 = ga[1];
      s16x8 vb0, vb1;
      if (B_F32) {
        const float4* gb = (const float4*)((const float*)Bp + (size_t)(n0 + srow) * K + k0 + shalf * 16);
        float4 b0 = gb[0], b1 = gb[1], b2 = gb[2], b3 = gb[3];
        vb0[0]=f2bf(b0.x); vb0[1]=f2bf(b0.y); vb0[2]=f2bf(b0.z); vb0[3]=f2bf(b0.w);
        vb0[4]=f2bf(b1.x); vb0[5]=f2bf(b1.y); vb0[6]=f2bf(b1.z); vb0[7]=f2bf(b1.w);
        vb1[0]=f2bf(b2.x); vb1[1]=f2bf(b2.y); vb1[2]=f2bf(b2.z); vb1[3]=f2bf(b2.w);
        vb1[4]=f2bf(b3.x); vb1[5]=f2bf(b3.y); vb1[6]=f2bf(b3.z); vb1[7]=f2bf(b3.w);
      } else {
        const s16x8* gb = (const s16x8*)((const short*)Bp + (size_t)(n0 + srow) * K + k0 + shalf * 16);
        vb0 = gb[0]; vb1 = gb[1];
      }
      *(s16x8*)&As[swz(srow, shalf * 2)]     = va0;
      *(s16x8*)&As[swz(srow, shalf * 2 + 1)] = va1;
      *(s16x8*)&Bs[swz(srow, shalf * 2)]     = vb0;
      *(s16x8*)&Bs[swz(srow, shalf * 2 + 1)] = vb1;
    }
    __syncthreads();
    const int q = lane >> 4, r16 = lane & 15;
    s16x8 af[4], bfr[4];
#pragma unroll
    for (int i = 0; i < 4; ++i) {
      af[i]  = *(const s16x8*)&As[swz(wm * 64 + i * 16 + r16, q)];
      bfr[i] = *(const s16x8*)&Bs[swz(wn * 64 + i * 16 + r16, q)];
    }
#pragma unroll
    for (int i = 0; i < 4; ++i)
#pragma unroll
      for (int j = 0; j < 4; ++j)
        acc[i][j] = __builtin_amdgcn_mfma_f32_16x16x32_bf16(af[i], bfr[j], acc[i][j], 0, 0, 0);
    __syncthreads();
  }
  const int q = lane >> 4, r16 = lane & 15;
#pragma unroll
  for (int i = 0; i < 4; ++i)
#pragma unroll
    for (int j = 0; j < 4; ++j)
#pragma unroll
      for (int r = 0; r < 4; ++r) {
        int row = m0 + wm * 64 + i * 16 + q * 4 + r;
        int col = n0 + wn * 64 + j * 16 + r16;
        float v = acc[i][j][r];
        if (C_BF16) ((short*)Cp)[(size_t)row * ldc + col] = f2bf(v);
        else        ((float*)Cp)[(size_t)row * ldc + col] = v;
      }
}

// ---------- persistent scan: 64 blocks x 512 threads, hand-rolled barrier ----------
// Per step: A) gates = acat @ Wcat^T, out-split 64x32 per block, full K
//           B) cell (c in registers) + attention + u=[a|h] + next-y, batch-split
//           C) o = tanh(u @ Wv^T), out-split 64x32 on blocks 0..15
__global__ __launch_bounds__(512, 1) void k_scan2(char* ws, const float* __restrict__ dic) {
  const int blk = blockIdx.x, tid = threadIdx.x;
  const int wv = tid >> 6, lane = tid & 63;
  const int q = lane >> 4, r16 = lane & 15;
  const int wm = wv >> 1, wn = wv & 1;

  const float* bs = (const float*)(ws + OFF_BS);
  const float* mf = (const float*)(ws + OFF_MASK);
  const short* Wcat = (const short*)(ws + OFF_WCAT);
  const short* Wv   = (const short*)(ws + OFF_WV);
  const short* ehb  = (const short*)(ws + OFF_EHB);
  const short* encp = (const short*)(ws + OFF_ENCP);
  const short* yb   = (const short*)(ws + OFF_YB);
  short* acat = (short*)(ws + OFF_ACAT);
  short* u    = (short*)(ws + OFF_U);
  short* OB   = (short*)(ws + OFF_OB);
  float* gp   = (float*)(ws + OFF_GP);
  unsigned* bcnt = (unsigned*)(ws + OFF_OTP);
  unsigned* bgen = (unsigned*)(ws + OFF_OTP + 4);

  __shared__ short As[64 * 32];   // 4 KB
  __shared__ short Bs[32 * 32];   // 2 KB
  __shared__ float hs[512];
  __shared__ float es[128];
  __shared__ float ps[512];
  __shared__ float red[2];

  float c_reg = dic[blk * 512 + tid];   // cell state: block == batch row, thread == j

  for (int t = 0; t < NSTEP; ++t) {
    // ---- Phase A: gates slice [64 x 32] at n0 = blk*32, K = 1536 ----
    {
      const int n0 = blk * 32;
      fx4 acc = {};
      for (int kt = 0; kt < 48; ++kt) {
        int k0 = kt * 32;
        if (tid < 256) {
          int ar = tid >> 2, ac = tid & 3;
          *(s16x8*)&As[swz(ar, ac)] = *(const s16x8*)(acat + ar * 1536 + k0 + ac * 8);
        } else if (tid < 384) {
          int l = tid - 256, br = l >> 2, bc = l & 3;
          *(s16x8*)&Bs[swz(br, bc)] = *(const s16x8*)(Wcat + (size_t)(n0 + br) * 1536 + k0 + bc * 8);
        }
        __syncthreads();
        s16x8 af = *(const s16x8*)&As[swz(wm * 16 + r16, q)];
        s16x8 bf = *(const s16x8*)&Bs[swz(wn * 16 + r16, q)];
        acc = __builtin_amdgcn_mfma_f32_16x16x32_bf16(af, bf, acc, 0, 0, 0);
        __syncthreads();
      }
#pragma unroll
      for (int r = 0; r < 4; ++r) {
        int m = wm * 16 + q * 4 + r, n = n0 + wn * 16 + r16;
        gp[m * 2048 + n] = acc[r];
      }
    }
    gridbar(bcnt, bgen);   // gates visible

    // ---- Phase B: cell + attention for batch b = blk ----
    {
      const int b = blk;
      {
        int j = tid;
        float g0 = bs[j]        + gp[b * 2048 + j];
        float g1 = bs[j + 512]  + gp[b * 2048 + j + 512];
        float g2 = bs[j + 1024] + gp[b * 2048 + j + 1024];
        float g3 = bs[j + 1536] + gp[b * 2048 + j + 1536];
        float ig = 1.f / (1.f + __expf(-g0));
        float fg = 1.f / (1.f + __expf(-g1));
        float gg = tanhf(g2);
        float og = 1.f / (1.f + __expf(-g3));
        c_reg = fg * c_reg + ig * gg;
        float hh = og * tanhf(c_reg);
        hs[j] = hh;
        short hb = f2bf(hh);
        acat[b * 1536 + 1024 + j] = hb;
        u[b * 1536 + 1024 + j] = hb;
      }
      if (t < 31 && tid < 64)   // next token embedding into own acat.y row
        *(s16x8*)(acat + b * 1536 + tid * 8) =
            *(const s16x8*)(yb + (size_t)(t + 1) * 32768 + b * 512 + tid * 8);
      __syncthreads();
      // e_t: s = tid>>2, quarter-dot of 128
      {
        int s = tid >> 2, qq = tid & 3;
        const short* er = encp + ((size_t)b * 128 + s) * 512 + qq * 128;
        const float* hp = hs + qq * 128;
        float a0 = 0.f, a1 = 0.f, a2 = 0.f, a3 = 0.f;
        for (int k = 0; k < 128; k += 32) {
          s16x8 v0 = *(const s16x8*)(er + k);
          s16x8 v1 = *(const s16x8*)(er + k + 8);
          s16x8 v2 = *(const s16x8*)(er + k + 16);
          s16x8 v3 = *(const s16x8*)(er + k + 24);
#pragma unroll
          for (int jj = 0; jj < 8; ++jj) {
            a0 += bf2f(v0[jj]) * hp[k + jj];
            a1 += bf2f(v1[jj]) * hp[k + 8 + jj];
            a2 += bf2f(v2[jj]) * hp[k + 16 + jj];
            a3 += bf2f(v3[jj]) * hp[k + 24 + jj];
          }
        }
        ps[tid] = (a0 + a1) + (a2 + a3);
      }
      __syncthreads();
      if (tid < 128) {
        float e = ps[4 * tid] + ps[4 * tid + 1] + ps[4 * tid + 2] + ps[4 * tid + 3];
        if (mf[b * 128 + tid] > 0.5f) e = -1e30f;
        es[tid] = e;
      }
      __syncthreads();
      if (tid < 64) {
        float m = fmaxf(es[tid], es[tid + 64]);
        for (int off = 32; off; off >>= 1) m = fmaxf(m, __shfl_xor(m, off));
        if (tid == 0) red[0] = m;
      }
      __syncthreads();
      float mM = red[0];
      if (tid < 128) es[tid] = __expf(es[tid] - mM);
      __syncthreads();
      if (tid < 64) {
        float s2 = es[tid] + es[tid + 64];
        for (int off = 32; off; off >>= 1) s2 += __shfl_xor(s2, off);
        if (tid == 0) red[1] = s2;
      }
      __syncthreads();
      float inv = 1.f / red[1];
      if (tid < 128) es[tid] *= inv;   // alpha
      __syncthreads();
      // a_t: thread handles k = 2*tid, 2*tid+1 (dword loads, coalesced)
      {
        const unsigned* col = (const unsigned*)(ehb + (size_t)b * 128 * 1024) + tid;
        float a0 = 0.f, a1 = 0.f, a2 = 0.f, a3 = 0.f;
        for (int s = 0; s < 128; s += 2) {
          unsigned w0 = col[(size_t)s * 512];
          unsigned w1 = col[(size_t)(s + 1) * 512];
          float al0 = es[s], al1 = es[s + 1];
          a0 += al0 * bf2f((short)(w0 & 0xffffu));
          a1 += al0 * bf2f((short)(w0 >> 16));
          a2 += al1 * bf2f((short)(w1 & 0xffffu));
          a3 += al1 * bf2f((short)(w1 >> 16));
        }
        u[b * 1536 + 2 * tid]     = f2bf(a0 + a2);
        u[b * 1536 + 2 * tid + 1] = f2bf(a1 + a3);
      }
    }
    gridbar(bcnt, bgen);   // u complete

    // ---- Phase C: o = tanh(u @ Wv^T), blocks 0..15, tile 64 x 32 ----
    if (blk < 16) {
      const int n0 = blk * 32;
      fx4 acc = {};
      for (int kt = 0; kt < 48; ++kt) {
        int k0 = kt * 32;
        if (tid < 256) {
          int ar = tid >> 2, ac = tid & 3;
          *(s16x8*)&As[swz(ar, ac)] = *(const s16x8*)(u + ar * 1536 + k0 + ac * 8);
        } else if (tid < 384) {
          int l = tid - 256, br = l >> 2, bc = l & 3;
          *(s16x8*)&Bs[swz(br, bc)] = *(const s16x8*)(Wv + (size_t)(n0 + br) * 1536 + k0 + bc * 8);
        }
        __syncthreads();
        s16x8 af = *(const s16x8*)&As[swz(wm * 16 + r16, q)];
        s16x8 bf = *(const s16x8*)&Bs[swz(wn * 16 + r16, q)];
        acc = __builtin_amdgcn_mfma_f32_16x16x32_bf16(af, bf, acc, 0, 0, 0);
        __syncthreads();
      }
#pragma unroll
      for (int r = 0; r < 4; ++r) {
        int m = wm * 16 + q * 4 + r, n = n0 + wn * 16 + r16;
        short ob = f2bf(tanhf(acc[r]));
        OB[(size_t)t * 32768 + m * 512 + n] = ob;
        acat[m * 1536 + 512 + n] = ob;   // o_prev for next step
      }
    }
    gridbar(bcnt, bgen);   // o visible for next gates
  }
}

extern "C" void kernel_launch(void* const* d_in, const int* in_sizes, int n_in,
                              void* d_out, int out_size, void* d_ws, size_t ws_size,
                              hipStream_t stream) {
  const int*   tgt   = (const int*)d_in[0];
  const float* ench  = (const float*)d_in[1];
  const float* dih   = (const float*)d_in[2];
  const float* dic   = (const float*)d_in[3];
  const unsigned char* mask = (const unsigned char*)d_in[4];
  const float* embed = (const float*)d_in[5];
  const float* W_ih  = (const float*)d_in[6];
  const float* W_hh  = (const float*)d_in[7];
  const float* b_ih  = (const float*)d_in[8];
  const float* b_hh  = (const float*)d_in[9];
  const float* W_att = (const float*)d_in[10];
  const float* W_v   = (const float*)d_in[11];
  const float* W_out = (const float*)d_in[12];
  char* ws = (char*)d_ws;

  hipLaunchKernelGGL(k_setup, dim3(8192), dim3(256), 0, stream,
                     tgt, ench, dih, dic, embed, W_ih, W_hh, b_ih, b_hh, W_v, mask, ws);
  // enc_proj: [8192x1024] x [512x1024]^T -> bf16 [8192][512]
  hipLaunchKernelGGL((k_gemm128<true, true>), dim3(64, 4), dim3(256), 0, stream,
                     (const short*)(ws + OFF_EHB), (const void*)W_att, (void*)(ws + OFF_ENCP), 1024, 512);
  // persistent scan: cooperative launch for co-residency guarantee, but the
  // kernel uses a hand-rolled agent-scope barrier (NOT cg::grid.sync, which
  // measured ~80us/sync in round 7). Fallback: ordinary launch (64 blocks on
  // 256 CUs are co-resident in practice).
  {
    char* wsp = ws;
    const float* dicp = dic;
    void* kargs[] = { (void*)&wsp, (void*)&dicp };
    hipError_t cerr = hipLaunchCooperativeKernel((const void*)k_scan2, dim3(64), dim3(512),
                                                 kargs, 0, stream);
    if (cerr != hipSuccess) {
      hipLaunchKernelGGL(k_scan2, dim3(64), dim3(512), 0, stream, ws, dic);
    }
  }
  // W_out -> bf16 into dead scan scratch, then P = O[2048x512] x W_out_bf16^T -> f32 d_out
  hipLaunchKernelGGL(k_castw, dim3(8000), dim3(256), 0, stream, W_out, (short*)(ws + OFF_WCAT));
  hipLaunchKernelGGL((k_gemm128<false, false>), dim3(16, 250), dim3(256), 0, stream,
                     (const short*)(ws + OFF_OB), (const void*)(ws + OFF_WCAT), d_out, 512, 32000);
}